// Round 2
// baseline (1204.185 us; speedup 1.0000x reference)
//
#include <hip/hip_runtime.h>

typedef unsigned short ushort_t;
typedef __attribute__((ext_vector_type(8))) short bf16x8;
typedef __attribute__((ext_vector_type(4))) short bf16x4;
typedef __attribute__((ext_vector_type(4))) float f32x4;
typedef __attribute__((ext_vector_type(4))) unsigned short u16x4;
typedef __attribute__((ext_vector_type(4))) unsigned int u32x4;

#define DEV __device__ __forceinline__

// ---------- helpers ----------
DEV ushort_t f2bf(float f) {
  union { float f; unsigned int u; } a; a.f = f;
  unsigned int u = a.u;
  unsigned int r = (u + 0x7fffu + ((u >> 16) & 1u)) >> 16;  // RNE
  return (ushort_t)r;
}
DEV float bf2f(ushort_t b) {
  union { float f; unsigned int u; } a; a.u = ((unsigned int)b) << 16;
  return a.f;
}
DEV void gload_lds16(const void* g, void* l) {
  __builtin_amdgcn_global_load_lds((const __attribute__((address_space(1))) void*)g,
                                   (__attribute__((address_space(3))) void*)l, 16, 0, 0);
}

// ---------- f32 -> bf16 convert ----------
__global__ __launch_bounds__(256) void f2b_kernel(const float* __restrict__ in,
                                                  ushort_t* __restrict__ out, int n) {
  int base = (blockIdx.x * 256 + threadIdx.x) * 4;
  if (base >= n) return;
  f32x4 v = *(const f32x4*)(in + base);
  u16x4 o;
  o.x = f2bf(v.x); o.y = f2bf(v.y); o.z = f2bf(v.z); o.w = f2bf(v.w);
  *(u16x4*)(out + base) = o;
}

// ---------- lambda weights ----------
__global__ void lam_kernel(const float* __restrict__ lambdas, float* __restrict__ lam) {
  if (threadIdx.x == 0 && blockIdx.x == 0) {
    float l0 = 1.f / (1.f + __expf(-lambdas[0]));
    float l1 = 1.f / (1.f + __expf(-lambdas[1]));
    float l2 = 1.f / (1.f + __expf(-lambdas[2]));
    float mean = (l0 + l1 + l2) * (1.f / 3.f);
    float d0 = l0 - mean, d1 = l1 - mean, d2 = l2 - mean;
    float var = (d0 * d0 + d1 * d1 + d2 * d2) * (1.f / 3.f);
    float rs = rsqrtf(var + 1e-5f);
    lam[0] = d0 * rs; lam[1] = d1 * rs; lam[2] = d2 * rs;
  }
}

// ---------- GEMM core: C[128x128 tile] = A[M,K] * B[N,K]^T, bf16, MFMA ----------
DEV void gemm_core(const ushort_t* __restrict__ A, const ushort_t* __restrict__ Bm,
                   ushort_t* lsA, ushort_t* lsB, int bm, int bn, f32x4 (&acc)[4][4]) {
  const int K = 2048;
  int tid = threadIdx.x;
  int w = tid >> 6, lane = tid & 63;
  int g = lane >> 4, r = lane & 15;
  int wm = w >> 1, wn = w & 1;
#pragma unroll
  for (int i = 0; i < 4; ++i)
#pragma unroll
    for (int j = 0; j < 4; ++j) acc[i][j] = 0.f;

  for (int kk = 0; kk < K; kk += 32) {
    __syncthreads();  // prev compute done before LDS overwrite
#pragma unroll
    for (int j2 = 0; j2 < 2; ++j2) {
      int eb = w * 1024 + j2 * 512;          // wave-uniform element base
      int ebl = eb + lane * 8;               // this lane's element
      int rr = ebl >> 5, cc = ebl & 31;
      gload_lds16(A + (size_t)(bm * 128 + rr) * K + kk + cc, lsA + eb);
      gload_lds16(Bm + (size_t)(bn * 128 + rr) * K + kk + cc, lsB + eb);
    }
    __syncthreads();  // vmcnt(0) drain -> LDS tile ready
    bf16x8 af[4], bfr[4];
#pragma unroll
    for (int i = 0; i < 4; ++i)
      af[i] = *(const bf16x8*)(lsA + (wm * 64 + i * 16 + r) * 32 + g * 8);
#pragma unroll
    for (int j = 0; j < 4; ++j)
      bfr[j] = *(const bf16x8*)(lsB + (wn * 64 + j * 16 + r) * 32 + g * 8);
#pragma unroll
    for (int i = 0; i < 4; ++i)
#pragma unroll
      for (int j = 0; j < 4; ++j)
        acc[i][j] = __builtin_amdgcn_mfma_f32_16x16x32_bf16(af[i], bfr[j], acc[i][j], 0, 0, 0);
  }
}

// fused QKV GEMM: grid.x = 48 (16 col-tiles x 3 outputs), grid.y = 16 row-tiles.
// K/V outputs are written into cache slot rows (b*Lkv + t); Q uses L=1024.
__global__ __launch_bounds__(256) void gemm_qkv(
    const ushort_t* __restrict__ A,
    const ushort_t* __restrict__ Bq, const ushort_t* __restrict__ Bk, const ushort_t* __restrict__ Bv,
    ushort_t* __restrict__ Cq, ushort_t* __restrict__ Ck, ushort_t* __restrict__ Cv, int Lkv) {
  __shared__ __align__(16) ushort_t lsA[4096];
  __shared__ __align__(16) ushort_t lsB[4096];
  int sel = blockIdx.x >> 4, bn = blockIdx.x & 15, bm = blockIdx.y;
  const ushort_t* Bm = (sel == 0) ? Bq : (sel == 1) ? Bk : Bv;
  ushort_t* C = (sel == 0) ? Cq : (sel == 1) ? Ck : Cv;
  int Lsel = (sel == 0) ? 1024 : Lkv;
  f32x4 acc[4][4];
  gemm_core(A, Bm, lsA, lsB, bm, bn, acc);
  int lane = threadIdx.x & 63, w = threadIdx.x >> 6;
  int g = lane >> 4, r = lane & 15, wm = w >> 1, wn = w & 1;
#pragma unroll
  for (int i = 0; i < 4; ++i)
#pragma unroll
    for (int j = 0; j < 4; ++j) {
      int row0 = bm * 128 + wm * 64 + i * 16 + g * 4;
      int col = bn * 128 + wn * 64 + j * 16 + r;
#pragma unroll
      for (int t = 0; t < 4; ++t) {
        int row = row0 + t;
        int b2 = row >> 10, t2 = row & 1023;
        C[(size_t)(b2 * Lsel + t2) * 2048 + col] = f2bf(acc[i][j][t]);
      }
    }
}

// single GEMM with f32 output (final projection)
__global__ __launch_bounds__(256) void gemm_bt_f32(
    const ushort_t* __restrict__ A, const ushort_t* __restrict__ Bm, float* __restrict__ C) {
  __shared__ __align__(16) ushort_t lsA[4096];
  __shared__ __align__(16) ushort_t lsB[4096];
  int bn = blockIdx.x, bm = blockIdx.y;
  f32x4 acc[4][4];
  gemm_core(A, Bm, lsA, lsB, bm, bn, acc);
  int lane = threadIdx.x & 63, w = threadIdx.x >> 6;
  int g = lane >> 4, r = lane & 15, wm = w >> 1, wn = w & 1;
#pragma unroll
  for (int i = 0; i < 4; ++i)
#pragma unroll
    for (int j = 0; j < 4; ++j) {
      int row0 = bm * 128 + wm * 64 + i * 16 + g * 4;
      int col = bn * 128 + wn * 64 + j * 16 + r;
#pragma unroll
      for (int t = 0; t < 4; ++t)
        C[(size_t)(row0 + t) * 2048 + col] = acc[i][j][t];
    }
}

// ---------- rope segment: dst[b, dpos0+p, :] = rope(src[b, s0+p, :], pos=dpos0+p) ----------
// layouts [B, Ls/Ld, H=16, D=128] bf16; grid = 2*cnt blocks, 256 threads.
// Safe in-place when src==dst, s0==dpos0, Ls==Ld.
__global__ __launch_bounds__(256) void rope_seg(const ushort_t* __restrict__ src, ushort_t* __restrict__ dst,
                                                const float* __restrict__ cosT, const float* __restrict__ sinT,
                                                int Ls, int s0, int Ld, int dpos0, int cnt) {
  int bp = blockIdx.x;
  int b = bp / cnt, pidx = bp % cnt;
  int pos = dpos0 + pidx;
  int pi = threadIdx.x * 4;         // pair index 0..1023
  int h = pi >> 6, d = pi & 63;
  const ushort_t* s_ = src + ((size_t)(b * Ls + s0 + pidx) * 16 + h) * 128 + d;
  ushort_t* d_ = dst + ((size_t)(b * Ld + pos) * 16 + h) * 128 + d;
  f32x4 c4 = *(const f32x4*)(cosT + (size_t)pos * 64 + d);
  f32x4 s4 = *(const f32x4*)(sinT + (size_t)pos * 64 + d);
  u16x4 x1 = *(const u16x4*)(s_);
  u16x4 x2 = *(const u16x4*)(s_ + 64);
  u16x4 o1, o2;
#pragma unroll
  for (int k = 0; k < 4; ++k) {
    float a = bf2f(x1[k]), bb = bf2f(x2[k]);
    o1[k] = f2bf(a * c4[k] - bb * s4[k]);
    o2[k] = f2bf(a * s4[k] + bb * c4[k]);
  }
  *(u16x4*)d_ = o1;
  *(u16x4*)(d_ + 64) = o2;
}

// ---------- row copy segment ----------
__global__ __launch_bounds__(256) void copy_seg(const ushort_t* __restrict__ src, ushort_t* __restrict__ dst,
                                                int Ls, int s0, int Ld, int dpos0, int cnt) {
  int bp = blockIdx.x;
  int b = bp / cnt, pidx = bp % cnt;
  const u32x4* s = (const u32x4*)(src + (size_t)(b * Ls + s0 + pidx) * 2048);
  u32x4* d = (u32x4*)(dst + (size_t)(b * Ld + dpos0 + pidx) * 2048);
  d[threadIdx.x] = s[threadIdx.x];
}

// ---------- flash attention: per-wave 16-row q tile, swapped QK^T ----------
// Q [B,1024,16,128], K/V [B,Lk,16,128] bf16; O [B,1024,16,128] f32
__global__ __launch_bounds__(256) void attn_kernel(
    const ushort_t* __restrict__ Q, const ushort_t* __restrict__ Kc, const ushort_t* __restrict__ Vc,
    float* __restrict__ Oout, int Lk) {
  const float sc = 0.08838834764831843f;  // 1/sqrt(128)
  int wid = blockIdx.x * 4 + (threadIdx.x >> 6);
  int lane = threadIdx.x & 63;
  int qt = wid & 63, h = (wid >> 6) & 15, b = wid >> 10;
  int g = lane >> 4, r = lane & 15;
  int off = Lk - 1024;

  const ushort_t* qbase = Q + ((size_t)(b * 1024 + qt * 16 + r) * 16 + h) * 128;
  bf16x8 qf[4];
#pragma unroll
  for (int c = 0; c < 4; ++c) qf[c] = *(const bf16x8*)(qbase + c * 32 + g * 8);

  float m_run = -1e30f, l_run = 0.f;
  f32x4 o[8];
#pragma unroll
  for (int c = 0; c < 8; ++c) o[c] = 0.f;

  int kmax = qt * 16 + 15 + off;
  int nkt = (kmax >> 4) + 1;
  int qp = qt * 16 + r + off;  // causal limit for this lane's q-row

  for (int kt = 0; kt < nkt; ++kt) {
    const ushort_t* kb = Kc + ((size_t)(b * Lk + kt * 16 + r) * 16 + h) * 128;
    f32x4 st = 0.f;
#pragma unroll
    for (int c = 0; c < 4; ++c) {
      bf16x8 kf = *(const bf16x8*)(kb + c * 32 + g * 8);
      st = __builtin_amdgcn_mfma_f32_16x16x32_bf16(kf, qf[c], st, 0, 0, 0);
    }
    // st[j] = S^T[key = kt*16 + g*4 + j][q = qt*16 + r]
    float pv[4];
    float pmax = -1e30f;
    int kp0 = kt * 16 + g * 4;
#pragma unroll
    for (int j = 0; j < 4; ++j) {
      float s = st[j] * sc;
      if (kp0 + j > qp) s = -1e30f;   // bottom-right causal mask
      pv[j] = s;
      pmax = fmaxf(pmax, s);
    }
    pmax = fmaxf(pmax, __shfl_xor(pmax, 16, 64));
    pmax = fmaxf(pmax, __shfl_xor(pmax, 32, 64));
    float mnew = fmaxf(m_run, pmax);
    float corr = __expf(m_run - mnew);
    float psum = 0.f;
    ushort_t pb[4];
#pragma unroll
    for (int j = 0; j < 4; ++j) {
      float pe = __expf(pv[j] - mnew);
      psum += pe;
      pb[j] = f2bf(pe);
    }
    psum += __shfl_xor(psum, 16, 64);
    psum += __shfl_xor(psum, 32, 64);
    l_run = l_run * corr + psum;
    m_run = mnew;
    float c4[4];
#pragma unroll
    for (int t = 0; t < 4; ++t) c4[t] = __shfl(corr, g * 4 + t, 64);
#pragma unroll
    for (int c = 0; c < 8; ++c) {
#pragma unroll
      for (int t = 0; t < 4; ++t) o[c][t] *= c4[t];
    }
    // PV: A = P (m=q=r, k=key=g*4+j), B = V (k=key, n=d=c*16+r)
    bf16x4 pfrag;
#pragma unroll
    for (int j = 0; j < 4; ++j) pfrag[j] = (short)pb[j];
    const ushort_t* vb = Vc + ((size_t)(b * Lk + kt * 16 + g * 4) * 16 + h) * 128 + r;
#pragma unroll
    for (int c = 0; c < 8; ++c) {
      bf16x4 vf;
#pragma unroll
      for (int j = 0; j < 4; ++j) vf[j] = (short)vb[(size_t)j * 2048 + c * 16];
      o[c] = __builtin_amdgcn_mfma_f32_16x16x16bf16_1k(pfrag, vf, o[c], 0, 0, 0);
    }
  }
  float linv = 1.f / l_run;
  float l4[4];
#pragma unroll
  for (int t = 0; t < 4; ++t) l4[t] = __shfl(linv, g * 4 + t, 64);
#pragma unroll
  for (int c = 0; c < 8; ++c)
#pragma unroll
    for (int t = 0; t < 4; ++t)
      Oout[((size_t)(b * 1024 + qt * 16 + g * 4 + t) * 16 + h) * 128 + c * 16 + r] = o[c][t] * l4[t];
}

// ---------- RMS norm of attn row + weighted accumulate into total ----------
template <int FIRST>
__global__ __launch_bounds__(256) void rms_accum(const float* __restrict__ attn, const float* __restrict__ lnw,
                                                 const float* __restrict__ lam, int li,
                                                 float* __restrict__ total) {
  int row = blockIdx.x;
  const float* a = attn + (size_t)row * 2048;
  int t8 = threadIdx.x * 8;
  f32x4 v0 = *(const f32x4*)(a + t8);
  f32x4 v1 = *(const f32x4*)(a + t8 + 4);
  float ss = v0.x * v0.x + v0.y * v0.y + v0.z * v0.z + v0.w * v0.w +
             v1.x * v1.x + v1.y * v1.y + v1.z * v1.z + v1.w * v1.w;
#pragma unroll
  for (int m = 1; m < 64; m <<= 1) ss += __shfl_xor(ss, m, 64);
  __shared__ float red[4];
  int w = threadIdx.x >> 6, lane = threadIdx.x & 63;
  if (lane == 0) red[w] = ss;
  __syncthreads();
  ss = red[0] + red[1] + red[2] + red[3];
  float s = rsqrtf(ss * (1.f / 2048.f) + 1e-5f) * lam[li];
  f32x4 w0 = *(const f32x4*)(lnw + t8);
  f32x4 w1 = *(const f32x4*)(lnw + t8 + 4);
  float* o = total + (size_t)row * 2048 + t8;
  f32x4 r0, r1;
#pragma unroll
  for (int k = 0; k < 4; ++k) { r0[k] = v0[k] * s * w0[k]; r1[k] = v1[k] * s * w1[k]; }
  if (!FIRST) {
    f32x4 p0 = *(const f32x4*)(o);
    f32x4 p1 = *(const f32x4*)(o + 4);
#pragma unroll
    for (int k = 0; k < 4; ++k) { r0[k] += p0[k]; r1[k] += p1[k]; }
  }
  *(f32x4*)(o) = r0;
  *(f32x4*)(o + 4) = r1;
}

// ---------- final: y = rms(total + alpha*x)*flw -> bf16 ----------
__global__ __launch_bounds__(256) void final_norm(const float* __restrict__ total, const float* __restrict__ x,
                                                  const float* __restrict__ alphap, const float* __restrict__ flw,
                                                  ushort_t* __restrict__ ybf) {
  int row = blockIdx.x;
  float al = alphap[0];
  int t8 = threadIdx.x * 8;
  const float* tp = total + (size_t)row * 2048 + t8;
  const float* xp = x + (size_t)row * 2048 + t8;
  f32x4 t0 = *(const f32x4*)(tp);
  f32x4 t1 = *(const f32x4*)(tp + 4);
  f32x4 x0 = *(const f32x4*)(xp);
  f32x4 x1 = *(const f32x4*)(xp + 4);
  float y[8];
#pragma unroll
  for (int k = 0; k < 4; ++k) { y[k] = t0[k] + al * x0[k]; y[4 + k] = t1[k] + al * x1[k]; }
  float ss = 0.f;
#pragma unroll
  for (int k = 0; k < 8; ++k) ss += y[k] * y[k];
#pragma unroll
  for (int m = 1; m < 64; m <<= 1) ss += __shfl_xor(ss, m, 64);
  __shared__ float red[4];
  int w = threadIdx.x >> 6, lane = threadIdx.x & 63;
  if (lane == 0) red[w] = ss;
  __syncthreads();
  ss = red[0] + red[1] + red[2] + red[3];
  float s = rsqrtf(ss * (1.f / 2048.f) + 1e-5f);
  f32x4 w0 = *(const f32x4*)(flw + t8);
  f32x4 w1 = *(const f32x4*)(flw + t8 + 4);
  u16x4 o0, o1;
#pragma unroll
  for (int k = 0; k < 4; ++k) {
    o0[k] = f2bf(y[k] * s * w0[k]);
    o1[k] = f2bf(y[4 + k] * s * w1[k]);
  }
  *(u16x4*)(ybf + (size_t)row * 2048 + t8) = o0;
  *(u16x4*)(ybf + (size_t)row * 2048 + t8 + 4) = o1;
}

// ---------- host ----------
extern "C" void kernel_launch(void* const* d_in, const int* in_sizes, int n_in,
                              void* d_out, int out_size, void* d_ws, size_t ws_size,
                              hipStream_t stream) {
  const float* x = (const float*)d_in[0];
  const float* cosT = (const float*)d_in[1];
  const float* sinT = (const float*)d_in[2];
  const float* wq = (const float*)d_in[3];
  const float* wk = (const float*)d_in[4];
  const float* wv = (const float*)d_in[5];
  const float* lnw = (const float*)d_in[6];
  const float* lambdas = (const float*)d_in[7];
  const float* w_out = (const float*)d_in[8];
  const float* flw = (const float*)d_in[9];
  const float* alpha = (const float*)d_in[10];

  const size_t ME = 4194304ull;  // 2048*2048 elements
  char* p = (char*)d_ws;
  size_t off = 0;
  auto alc = [&](size_t bytes) -> void* {
    void* r = p + off;
    off += (bytes + 255) & ~(size_t)255;
    return r;
  };
  // total scratch: ~184 MB
  ushort_t* xb = (ushort_t*)alc(ME * 2);        // 8 MB
  ushort_t* wl = (ushort_t*)alc(3 * ME * 2);    // 24 MB (per-layer wq,wk,wv; later w_out)
  ushort_t* q = (ushort_t*)alc(ME * 2);         // 8 MB (roped in place; later ybf)
  ushort_t* K0 = (ushort_t*)alc(ME * 2);        // 8 MB
  ushort_t* K1 = (ushort_t*)alc(2 * ME * 2);    // 16 MB
  ushort_t* K2 = (ushort_t*)alc(4 * ME * 2);    // 32 MB
  ushort_t* V0 = (ushort_t*)alc(ME * 2);        // 8 MB
  ushort_t* V1 = (ushort_t*)alc(2 * ME * 2);    // 16 MB
  ushort_t* V2 = (ushort_t*)alc(4 * ME * 2);    // 32 MB
  float* attn = (float*)alc(ME * 4);            // 16 MB
  float* total = (float*)alc(ME * 4);           // 16 MB
  float* lam = (float*)alc(256);
  ushort_t* ybf = q;                             // alias: q dead before final_norm

  f2b_kernel<<<4096, 256, 0, stream>>>(x, xb, 4194304);
  lam_kernel<<<1, 64, 0, stream>>>(lambdas, lam);

  ushort_t* Kc[3] = {K0, K1, K2};
  ushort_t* Vc[3] = {V0, V1, V2};

  for (int li = 0; li < 3; ++li) {
    int L = 1024 << li;
    size_t woff = (size_t)li * ME;
    // convert this layer's weights
    f2b_kernel<<<4096, 256, 0, stream>>>(wq + woff, wl, 4194304);
    f2b_kernel<<<4096, 256, 0, stream>>>(wk + woff, wl + ME, 4194304);
    f2b_kernel<<<4096, 256, 0, stream>>>(wv + woff, wl + 2 * ME, 4194304);
    // QKV; K/V land directly in cache rows [b, 0..1023]
    gemm_qkv<<<dim3(48, 16), 256, 0, stream>>>(xb, wl, wl + ME, wl + 2 * ME,
                                               q, Kc[li], Vc[li], L);
    // rope Q in place (positions 0..1023)
    rope_seg<<<2048, 256, 0, stream>>>(q, q, cosT, sinT, 1024, 0, 1024, 0, 1024);
    // rope fresh K segment in place (positions 0..1023)
    rope_seg<<<2048, 256, 0, stream>>>(Kc[li], Kc[li], cosT, sinT, L, 0, L, 0, 1024);
    if (li == 1) {
      // K1[1024..2047] = rope(K0, pos 1024..2047); V1[1024..2047] = V0
      rope_seg<<<2048, 256, 0, stream>>>(K0, K1, cosT, sinT, 1024, 0, 2048, 1024, 1024);
      copy_seg<<<2048, 256, 0, stream>>>(V0, V1, 1024, 0, 2048, 1024, 1024);
    } else if (li == 2) {
      // K2[1024..2047] = K1[1024..2047] (identical composed rotation)
      copy_seg<<<2048, 256, 0, stream>>>(K1, K2, 2048, 1024, 4096, 1024, 1024);
      // K2[2048..4095] = rope(K1[0..2047], pos 2048..4095)
      rope_seg<<<4096, 256, 0, stream>>>(K1, K2, cosT, sinT, 2048, 0, 4096, 2048, 2048);
      // V2[1024..2047] = V1[1024..2047] (= v0); V2[2048..4095] = V1[0..2047]
      copy_seg<<<2048, 256, 0, stream>>>(V1, V2, 2048, 1024, 4096, 1024, 1024);
      copy_seg<<<4096, 256, 0, stream>>>(V1, V2, 2048, 0, 4096, 2048, 2048);
    }
    attn_kernel<<<512, 256, 0, stream>>>(q, Kc[li], Vc[li], attn, L);
    if (li == 0)
      rms_accum<1><<<2048, 256, 0, stream>>>(attn, lnw, lam, 0, total);
    else
      rms_accum<0><<<2048, 256, 0, stream>>>(attn, lnw + (size_t)li * 2048, lam, li, total);
  }

  // final projection weight -> bf16 (reuse wl)
  f2b_kernel<<<4096, 256, 0, stream>>>(w_out, wl, 4194304);
  final_norm<<<2048, 256, 0, stream>>>(total, x, alpha, flw, ybf);
  gemm_bt_f32<<<dim3(16, 16), 256, 0, stream>>>(ybf, wl, (float*)d_out);
}

// Round 3
// 721.352 us; speedup vs baseline: 1.6693x; 1.6693x over previous
//
#include <hip/hip_runtime.h>

typedef unsigned short ushort_t;
typedef __attribute__((ext_vector_type(8))) short bf16x8;
typedef __attribute__((ext_vector_type(4))) short bf16x4;
typedef __attribute__((ext_vector_type(4))) float f32x4;
typedef __attribute__((ext_vector_type(4))) unsigned short u16x4;
typedef __attribute__((ext_vector_type(4))) unsigned int u32x4;

#define DEV __device__ __forceinline__

// ---------- helpers ----------
DEV ushort_t f2bf(float f) {
  union { float f; unsigned int u; } a; a.f = f;
  unsigned int u = a.u;
  unsigned int r = (u + 0x7fffu + ((u >> 16) & 1u)) >> 16;  // RNE
  return (ushort_t)r;
}
DEV float bf2f(ushort_t b) {
  union { float f; unsigned int u; } a; a.u = ((unsigned int)b) << 16;
  return a.f;
}
DEV void gload_lds16(const void* g, void* l) {
  __builtin_amdgcn_global_load_lds((const __attribute__((address_space(1))) void*)g,
                                   (__attribute__((address_space(3))) void*)l, 16, 0, 0);
}
// hardware transpose read: lane l, elem j <- lds_elems[(l&15) + j*16 + (l>>4)*64]
DEV bf16x4 tr16(const ushort_t* l) {
  unsigned a = (unsigned)(unsigned long long)(const __attribute__((address_space(3))) ushort_t*)l;
  bf16x4 d;
  asm volatile("ds_read_b64_tr_b16 %0, %1" : "=v"(d) : "v"(a));
  return d;
}

// ---------- f32 -> bf16 convert ----------
__global__ __launch_bounds__(256) void f2b_kernel(const float* __restrict__ in,
                                                  ushort_t* __restrict__ out, int n) {
  int base = (blockIdx.x * 256 + threadIdx.x) * 4;
  if (base >= n) return;
  f32x4 v = *(const f32x4*)(in + base);
  u16x4 o;
  o.x = f2bf(v.x); o.y = f2bf(v.y); o.z = f2bf(v.z); o.w = f2bf(v.w);
  *(u16x4*)(out + base) = o;
}

// ---------- lambda weights ----------
__global__ void lam_kernel(const float* __restrict__ lambdas, float* __restrict__ lam) {
  if (threadIdx.x == 0 && blockIdx.x == 0) {
    float l0 = 1.f / (1.f + __expf(-lambdas[0]));
    float l1 = 1.f / (1.f + __expf(-lambdas[1]));
    float l2 = 1.f / (1.f + __expf(-lambdas[2]));
    float mean = (l0 + l1 + l2) * (1.f / 3.f);
    float d0 = l0 - mean, d1 = l1 - mean, d2 = l2 - mean;
    float var = (d0 * d0 + d1 * d1 + d2 * d2) * (1.f / 3.f);
    float rs = rsqrtf(var + 1e-5f);
    lam[0] = d0 * rs; lam[1] = d1 * rs; lam[2] = d2 * rs;
  }
}

// ---------- GEMM core: C[128x128 tile] = A[M,K] * B[N,K]^T, bf16, MFMA ----------
DEV void gemm_core(const ushort_t* __restrict__ A, const ushort_t* __restrict__ Bm,
                   ushort_t* lsA, ushort_t* lsB, int bm, int bn, f32x4 (&acc)[4][4]) {
  const int K = 2048;
  int tid = threadIdx.x;
  int w = tid >> 6, lane = tid & 63;
  int g = lane >> 4, r = lane & 15;
  int wm = w >> 1, wn = w & 1;
#pragma unroll
  for (int i = 0; i < 4; ++i)
#pragma unroll
    for (int j = 0; j < 4; ++j) acc[i][j] = 0.f;

  for (int kk = 0; kk < K; kk += 32) {
    __syncthreads();  // prev compute done before LDS overwrite
#pragma unroll
    for (int j2 = 0; j2 < 2; ++j2) {
      int eb = w * 1024 + j2 * 512;          // wave-uniform element base
      int ebl = eb + lane * 8;               // this lane's element
      int rr = ebl >> 5, cc = ebl & 31;
      gload_lds16(A + (size_t)(bm * 128 + rr) * K + kk + cc, lsA + eb);
      gload_lds16(Bm + (size_t)(bn * 128 + rr) * K + kk + cc, lsB + eb);
    }
    __syncthreads();  // vmcnt(0) drain -> LDS tile ready
    bf16x8 af[4], bfr[4];
#pragma unroll
    for (int i = 0; i < 4; ++i)
      af[i] = *(const bf16x8*)(lsA + (wm * 64 + i * 16 + r) * 32 + g * 8);
#pragma unroll
    for (int j = 0; j < 4; ++j)
      bfr[j] = *(const bf16x8*)(lsB + (wn * 64 + j * 16 + r) * 32 + g * 8);
#pragma unroll
    for (int i = 0; i < 4; ++i)
#pragma unroll
      for (int j = 0; j < 4; ++j)
        acc[i][j] = __builtin_amdgcn_mfma_f32_16x16x32_bf16(af[i], bfr[j], acc[i][j], 0, 0, 0);
  }
}

// fused QKV GEMM: grid.x = 48 (16 col-tiles x 3 outputs), grid.y = 16 row-tiles.
__global__ __launch_bounds__(256) void gemm_qkv(
    const ushort_t* __restrict__ A,
    const ushort_t* __restrict__ Bq, const ushort_t* __restrict__ Bk, const ushort_t* __restrict__ Bv,
    ushort_t* __restrict__ Cq, ushort_t* __restrict__ Ck, ushort_t* __restrict__ Cv, int Lkv) {
  __shared__ __align__(16) ushort_t lsA[4096];
  __shared__ __align__(16) ushort_t lsB[4096];
  int sel = blockIdx.x >> 4, bn = blockIdx.x & 15, bm = blockIdx.y;
  const ushort_t* Bm = (sel == 0) ? Bq : (sel == 1) ? Bk : Bv;
  ushort_t* C = (sel == 0) ? Cq : (sel == 1) ? Ck : Cv;
  int Lsel = (sel == 0) ? 1024 : Lkv;
  f32x4 acc[4][4];
  gemm_core(A, Bm, lsA, lsB, bm, bn, acc);
  int lane = threadIdx.x & 63, w = threadIdx.x >> 6;
  int g = lane >> 4, r = lane & 15, wm = w >> 1, wn = w & 1;
#pragma unroll
  for (int i = 0; i < 4; ++i)
#pragma unroll
    for (int j = 0; j < 4; ++j) {
      int row0 = bm * 128 + wm * 64 + i * 16 + g * 4;
      int col = bn * 128 + wn * 64 + j * 16 + r;
#pragma unroll
      for (int t = 0; t < 4; ++t) {
        int row = row0 + t;
        int b2 = row >> 10, t2 = row & 1023;
        C[(size_t)(b2 * Lsel + t2) * 2048 + col] = f2bf(acc[i][j][t]);
      }
    }
}

// single GEMM with f32 output (final projection)
__global__ __launch_bounds__(256) void gemm_bt_f32(
    const ushort_t* __restrict__ A, const ushort_t* __restrict__ Bm, float* __restrict__ C) {
  __shared__ __align__(16) ushort_t lsA[4096];
  __shared__ __align__(16) ushort_t lsB[4096];
  int bn = blockIdx.x, bm = blockIdx.y;
  f32x4 acc[4][4];
  gemm_core(A, Bm, lsA, lsB, bm, bn, acc);
  int lane = threadIdx.x & 63, w = threadIdx.x >> 6;
  int g = lane >> 4, r = lane & 15, wm = w >> 1, wn = w & 1;
#pragma unroll
  for (int i = 0; i < 4; ++i)
#pragma unroll
    for (int j = 0; j < 4; ++j) {
      int row0 = bm * 128 + wm * 64 + i * 16 + g * 4;
      int col = bn * 128 + wn * 64 + j * 16 + r;
#pragma unroll
      for (int t = 0; t < 4; ++t)
        C[(size_t)(row0 + t) * 2048 + col] = acc[i][j][t];
    }
}

// ---------- rope segment ----------
__global__ __launch_bounds__(256) void rope_seg(const ushort_t* __restrict__ src, ushort_t* __restrict__ dst,
                                                const float* __restrict__ cosT, const float* __restrict__ sinT,
                                                int Ls, int s0, int Ld, int dpos0, int cnt) {
  int bp = blockIdx.x;
  int b = bp / cnt, pidx = bp % cnt;
  int pos = dpos0 + pidx;
  int pi = threadIdx.x * 4;         // pair index 0..1023
  int h = pi >> 6, d = pi & 63;
  const ushort_t* s_ = src + ((size_t)(b * Ls + s0 + pidx) * 16 + h) * 128 + d;
  ushort_t* d_ = dst + ((size_t)(b * Ld + pos) * 16 + h) * 128 + d;
  f32x4 c4 = *(const f32x4*)(cosT + (size_t)pos * 64 + d);
  f32x4 s4 = *(const f32x4*)(sinT + (size_t)pos * 64 + d);
  u16x4 x1 = *(const u16x4*)(s_);
  u16x4 x2 = *(const u16x4*)(s_ + 64);
  u16x4 o1, o2;
#pragma unroll
  for (int k = 0; k < 4; ++k) {
    float a = bf2f(x1[k]), bb = bf2f(x2[k]);
    o1[k] = f2bf(a * c4[k] - bb * s4[k]);
    o2[k] = f2bf(a * s4[k] + bb * c4[k]);
  }
  *(u16x4*)d_ = o1;
  *(u16x4*)(d_ + 64) = o2;
}

// ---------- row copy segment ----------
__global__ __launch_bounds__(256) void copy_seg(const ushort_t* __restrict__ src, ushort_t* __restrict__ dst,
                                                int Ls, int s0, int Ld, int dpos0, int cnt) {
  int bp = blockIdx.x;
  int b = bp / cnt, pidx = bp % cnt;
  const u32x4* s = (const u32x4*)(src + (size_t)(b * Ls + s0 + pidx) * 2048);
  u32x4* d = (u32x4*)(dst + (size_t)(b * Ld + dpos0 + pidx) * 2048);
  d[threadIdx.x] = s[threadIdx.x];
}

// ---------- flash attention v2: LDS-staged K/V shared by 4 waves ----------
// Block = 4 waves, one (b,h) + 4 consecutive 16-row q-tiles. KV tile = 32 keys.
// K in LDS row-major [32][128] with XOR-swizzled 16B chunks (chunk ^= row&7).
// V in LDS subtiled [d/16=8][k/4=8][4][16] -> ds_read_b64_tr_b16 gives V^T A-frags.
// PV computes O^T = V^T * P^T so P^T (swapped-QK^T output) is the B-frag in-register.
__global__ __launch_bounds__(256) void attn_kernel(
    const ushort_t* __restrict__ Q, const ushort_t* __restrict__ Kc, const ushort_t* __restrict__ Vc,
    float* __restrict__ Oout, int Lk) {
  __shared__ __align__(16) ushort_t lsK[4096];  // 8 KB
  __shared__ __align__(16) ushort_t lsV[4096];  // 8 KB
  const float sc = 0.08838834764831843f;  // 1/sqrt(128)

  // XCD-aware swizzle: 512 blocks, 8 XCDs -> 64 consecutive logical blocks per XCD
  int bid = (int)blockIdx.x;
  int swz = (bid & 7) * 64 + (bid >> 3);

  int w = threadIdx.x >> 6, lane = threadIdx.x & 63;
  int wid = swz * 4 + w;
  int qt = wid & 63, h = (wid >> 6) & 15, b = wid >> 10;
  int bq = swz & 15;
  int g = lane >> 4, r = lane & 15;
  int off = Lk - 1024;

  // Q fragments (B-operand of QK^T: B[k][n=r], q-row = qt*16+r)
  const ushort_t* qbase = Q + ((size_t)(b * 1024 + qt * 16 + r) * 16 + h) * 128;
  bf16x8 qf[4];
#pragma unroll
  for (int c = 0; c < 4; ++c) qf[c] = *(const bf16x8*)(qbase + c * 32 + g * 8);

  // staging source pointers (pre-swizzled per-lane global addresses)
  int t = threadIdx.x;
  int krow0 = t >> 4,        kc0 = (t & 15) ^ (krow0 & 7);
  int krow1 = (t + 256) >> 4, kc1 = (t & 15) ^ (krow1 & 7);
  const ushort_t* srcK0 = Kc + ((size_t)(b * Lk + krow0) * 16 + h) * 128 + kc0 * 8;
  const ushort_t* srcK1 = Kc + ((size_t)(b * Lk + krow1) * 16 + h) * 128 + kc1 * 8;
  int L0 = t, L1 = t + 256;
  int vrow0 = ((L0 >> 3) & 7) * 4 + ((L0 >> 1) & 3), vd0 = (L0 >> 6) * 16 + (L0 & 1) * 8;
  int vrow1 = ((L1 >> 3) & 7) * 4 + ((L1 >> 1) & 3), vd1 = (L1 >> 6) * 16 + (L1 & 1) * 8;
  const ushort_t* srcV0 = Vc + ((size_t)(b * Lk + vrow0) * 16 + h) * 128 + vd0;
  const ushort_t* srcV1 = Vc + ((size_t)(b * Lk + vrow1) * 16 + h) * 128 + vd1;
  ushort_t* dstK0 = lsK + (w * 64) * 8;
  ushort_t* dstK1 = lsK + (256 + w * 64) * 8;
  ushort_t* dstV0 = lsV + (w * 64) * 8;
  ushort_t* dstV1 = lsV + (256 + w * 64) * 8;
  const size_t adv = 32 * 2048;  // 32 kv rows per tile

  float m_run = -1e30f, l_run = 0.f;
  f32x4 o[8];
#pragma unroll
  for (int c = 0; c < 8; ++c) o[c] = 0.f;

  int qp = qt * 16 + r + off;                         // causal limit for q=r
  int nkt_w = ((qt * 16 + 15 + off) >> 5) + 1;        // this wave's tiles
  int nkt_blk = (((bq * 4 + 3) * 16 + 15 + off) >> 5) + 1;  // block max

  for (int kt = 0; kt < nkt_blk; ++kt) {
    __syncthreads();
    gload_lds16(srcK0, dstK0);
    gload_lds16(srcK1, dstK1);
    gload_lds16(srcV0, dstV0);
    gload_lds16(srcV1, dstV1);
    srcK0 += adv; srcK1 += adv; srcV0 += adv; srcV1 += adv;
    __syncthreads();
    if (kt < nkt_w) {
      // QK^T (swapped): st[ks] C[m=key][n=q]
      f32x4 st[2];
      st[0] = 0.f; st[1] = 0.f;
#pragma unroll
      for (int ks = 0; ks < 2; ++ks)
#pragma unroll
        for (int c = 0; c < 4; ++c) {
          bf16x8 kf = *(const bf16x8*)(lsK + (ks * 16 + r) * 128 + (((c * 32 + g * 8) ^ ((r & 7) * 8))));
          st[ks] = __builtin_amdgcn_mfma_f32_16x16x32_bf16(kf, qf[c], st[ks], 0, 0, 0);
        }
      // softmax over the 8 scores this lane holds (keys kt*32 + ks*16 + g*4 + j, q = r)
      float pv[2][4];
      float pmax = -1e30f;
#pragma unroll
      for (int ks = 0; ks < 2; ++ks)
#pragma unroll
        for (int j = 0; j < 4; ++j) {
          int key = kt * 32 + ks * 16 + g * 4 + j;
          float s = st[ks][j] * sc;
          if (key > qp) s = -1e30f;
          pv[ks][j] = s;
          pmax = fmaxf(pmax, s);
        }
      pmax = fmaxf(pmax, __shfl_xor(pmax, 16, 64));
      pmax = fmaxf(pmax, __shfl_xor(pmax, 32, 64));
      float mnew = fmaxf(m_run, pmax);
      float corr = __expf(m_run - mnew);
      float psum = 0.f;
      bf16x4 pf[2];
#pragma unroll
      for (int ks = 0; ks < 2; ++ks)
#pragma unroll
        for (int j = 0; j < 4; ++j) {
          float pe = __expf(pv[ks][j] - mnew);
          psum += pe;
          pf[ks][j] = (short)f2bf(pe);
        }
      psum += __shfl_xor(psum, 16, 64);
      psum += __shfl_xor(psum, 32, 64);
      l_run = l_run * corr + psum;
      m_run = mnew;
      // rescale O (q = r for every accumulator element -> per-lane scalar)
#pragma unroll
      for (int c = 0; c < 8; ++c)
#pragma unroll
        for (int tt = 0; tt < 4; ++tt) o[c][tt] *= corr;
      // PV: O^T[d][q] += V^T[d][k] * P^T[k][q]
#pragma unroll
      for (int dblk = 0; dblk < 8; ++dblk) {
        bf16x4 a0 = tr16(lsV + dblk * 512);
        bf16x4 a1 = tr16(lsV + dblk * 512 + 256);
        asm volatile("s_waitcnt lgkmcnt(0)" ::: "memory");
        __builtin_amdgcn_sched_barrier(0);
        o[dblk] = __builtin_amdgcn_mfma_f32_16x16x16bf16_1k(a0, pf[0], o[dblk], 0, 0, 0);
        o[dblk] = __builtin_amdgcn_mfma_f32_16x16x16bf16_1k(a1, pf[1], o[dblk], 0, 0, 0);
      }
    }
  }
  // epilogue: O^T frag -> O[q = qt*16+r][d = dblk*16 + g*4 + t]
  float linv = 1.f / l_run;
  float* ob = Oout + ((size_t)(b * 1024 + qt * 16 + r) * 16 + h) * 128;
#pragma unroll
  for (int dblk = 0; dblk < 8; ++dblk) {
    f32x4 res;
#pragma unroll
    for (int tt = 0; tt < 4; ++tt) res[tt] = o[dblk][tt] * linv;
    *(f32x4*)(ob + dblk * 16 + g * 4) = res;
  }
}

// ---------- RMS norm of attn row + weighted accumulate into total ----------
template <int FIRST>
__global__ __launch_bounds__(256) void rms_accum(const float* __restrict__ attn, const float* __restrict__ lnw,
                                                 const float* __restrict__ lam, int li,
                                                 float* __restrict__ total) {
  int row = blockIdx.x;
  const float* a = attn + (size_t)row * 2048;
  int t8 = threadIdx.x * 8;
  f32x4 v0 = *(const f32x4*)(a + t8);
  f32x4 v1 = *(const f32x4*)(a + t8 + 4);
  float ss = v0.x * v0.x + v0.y * v0.y + v0.z * v0.z + v0.w * v0.w +
             v1.x * v1.x + v1.y * v1.y + v1.z * v1.z + v1.w * v1.w;
#pragma unroll
  for (int m = 1; m < 64; m <<= 1) ss += __shfl_xor(ss, m, 64);
  __shared__ float red[4];
  int w = threadIdx.x >> 6, lane = threadIdx.x & 63;
  if (lane == 0) red[w] = ss;
  __syncthreads();
  ss = red[0] + red[1] + red[2] + red[3];
  float s = rsqrtf(ss * (1.f / 2048.f) + 1e-5f) * lam[li];
  f32x4 w0 = *(const f32x4*)(lnw + t8);
  f32x4 w1 = *(const f32x4*)(lnw + t8 + 4);
  float* o = total + (size_t)row * 2048 + t8;
  f32x4 r0, r1;
#pragma unroll
  for (int k = 0; k < 4; ++k) { r0[k] = v0[k] * s * w0[k]; r1[k] = v1[k] * s * w1[k]; }
  if (!FIRST) {
    f32x4 p0 = *(const f32x4*)(o);
    f32x4 p1 = *(const f32x4*)(o + 4);
#pragma unroll
    for (int k = 0; k < 4; ++k) { r0[k] += p0[k]; r1[k] += p1[k]; }
  }
  *(f32x4*)(o) = r0;
  *(f32x4*)(o + 4) = r1;
}

// ---------- final: y = rms(total + alpha*x)*flw -> bf16 ----------
__global__ __launch_bounds__(256) void final_norm(const float* __restrict__ total, const float* __restrict__ x,
                                                  const float* __restrict__ alphap, const float* __restrict__ flw,
                                                  ushort_t* __restrict__ ybf) {
  int row = blockIdx.x;
  float al = alphap[0];
  int t8 = threadIdx.x * 8;
  const float* tp = total + (size_t)row * 2048 + t8;
  const float* xp = x + (size_t)row * 2048 + t8;
  f32x4 t0 = *(const f32x4*)(tp);
  f32x4 t1 = *(const f32x4*)(tp + 4);
  f32x4 x0 = *(const f32x4*)(xp);
  f32x4 x1 = *(const f32x4*)(xp + 4);
  float y[8];
#pragma unroll
  for (int k = 0; k < 4; ++k) { y[k] = t0[k] + al * x0[k]; y[4 + k] = t1[k] + al * x1[k]; }
  float ss = 0.f;
#pragma unroll
  for (int k = 0; k < 8; ++k) ss += y[k] * y[k];
#pragma unroll
  for (int m = 1; m < 64; m <<= 1) ss += __shfl_xor(ss, m, 64);
  __shared__ float red[4];
  int w = threadIdx.x >> 6, lane = threadIdx.x & 63;
  if (lane == 0) red[w] = ss;
  __syncthreads();
  ss = red[0] + red[1] + red[2] + red[3];
  float s = rsqrtf(ss * (1.f / 2048.f) + 1e-5f);
  f32x4 w0 = *(const f32x4*)(flw + t8);
  f32x4 w1 = *(const f32x4*)(flw + t8 + 4);
  u16x4 o0, o1;
#pragma unroll
  for (int k = 0; k < 4; ++k) {
    o0[k] = f2bf(y[k] * s * w0[k]);
    o1[k] = f2bf(y[4 + k] * s * w1[k]);
  }
  *(u16x4*)(ybf + (size_t)row * 2048 + t8) = o0;
  *(u16x4*)(ybf + (size_t)row * 2048 + t8 + 4) = o1;
}

// ---------- host ----------
extern "C" void kernel_launch(void* const* d_in, const int* in_sizes, int n_in,
                              void* d_out, int out_size, void* d_ws, size_t ws_size,
                              hipStream_t stream) {
  const float* x = (const float*)d_in[0];
  const float* cosT = (const float*)d_in[1];
  const float* sinT = (const float*)d_in[2];
  const float* wq = (const float*)d_in[3];
  const float* wk = (const float*)d_in[4];
  const float* wv = (const float*)d_in[5];
  const float* lnw = (const float*)d_in[6];
  const float* lambdas = (const float*)d_in[7];
  const float* w_out = (const float*)d_in[8];
  const float* flw = (const float*)d_in[9];
  const float* alpha = (const float*)d_in[10];

  const size_t ME = 4194304ull;  // 2048*2048 elements
  char* p = (char*)d_ws;
  size_t off = 0;
  auto alc = [&](size_t bytes) -> void* {
    void* r = p + off;
    off += (bytes + 255) & ~(size_t)255;
    return r;
  };
  ushort_t* xb = (ushort_t*)alc(ME * 2);        // 8 MB
  ushort_t* wl = (ushort_t*)alc(3 * ME * 2);    // 24 MB (per-layer wq,wk,wv; later w_out)
  ushort_t* q = (ushort_t*)alc(ME * 2);         // 8 MB (roped in place; later ybf)
  ushort_t* K0 = (ushort_t*)alc(ME * 2);        // 8 MB
  ushort_t* K1 = (ushort_t*)alc(2 * ME * 2);    // 16 MB
  ushort_t* K2 = (ushort_t*)alc(4 * ME * 2);    // 32 MB
  ushort_t* V0 = (ushort_t*)alc(ME * 2);        // 8 MB
  ushort_t* V1 = (ushort_t*)alc(2 * ME * 2);    // 16 MB
  ushort_t* V2 = (ushort_t*)alc(4 * ME * 2);    // 32 MB
  float* attn = (float*)alc(ME * 4);            // 16 MB
  float* total = (float*)alc(ME * 4);           // 16 MB
  float* lam = (float*)alc(256);
  ushort_t* ybf = q;                             // alias: q dead before final_norm

  f2b_kernel<<<4096, 256, 0, stream>>>(x, xb, 4194304);
  lam_kernel<<<1, 64, 0, stream>>>(lambdas, lam);

  ushort_t* Kc[3] = {K0, K1, K2};
  ushort_t* Vc[3] = {V0, V1, V2};

  for (int li = 0; li < 3; ++li) {
    int L = 1024 << li;
    size_t woff = (size_t)li * ME;
    f2b_kernel<<<4096, 256, 0, stream>>>(wq + woff, wl, 4194304);
    f2b_kernel<<<4096, 256, 0, stream>>>(wk + woff, wl + ME, 4194304);
    f2b_kernel<<<4096, 256, 0, stream>>>(wv + woff, wl + 2 * ME, 4194304);
    gemm_qkv<<<dim3(48, 16), 256, 0, stream>>>(xb, wl, wl + ME, wl + 2 * ME,
                                               q, Kc[li], Vc[li], L);
    rope_seg<<<2048, 256, 0, stream>>>(q, q, cosT, sinT, 1024, 0, 1024, 0, 1024);
    rope_seg<<<2048, 256, 0, stream>>>(Kc[li], Kc[li], cosT, sinT, L, 0, L, 0, 1024);
    if (li == 1) {
      rope_seg<<<2048, 256, 0, stream>>>(K0, K1, cosT, sinT, 1024, 0, 2048, 1024, 1024);
      copy_seg<<<2048, 256, 0, stream>>>(V0, V1, 1024, 0, 2048, 1024, 1024);
    } else if (li == 2) {
      copy_seg<<<2048, 256, 0, stream>>>(K1, K2, 2048, 1024, 4096, 1024, 1024);
      rope_seg<<<4096, 256, 0, stream>>>(K1, K2, cosT, sinT, 2048, 0, 4096, 2048, 2048);
      copy_seg<<<2048, 256, 0, stream>>>(V1, V2, 2048, 1024, 4096, 1024, 1024);
      copy_seg<<<4096, 256, 0, stream>>>(V1, V2, 2048, 0, 4096, 2048, 2048);
    }
    attn_kernel<<<512, 256, 0, stream>>>(q, Kc[li], Vc[li], attn, L);
    if (li == 0)
      rms_accum<1><<<2048, 256, 0, stream>>>(attn, lnw, lam, 0, total);
    else
      rms_accum<0><<<2048, 256, 0, stream>>>(attn, lnw + (size_t)li * 2048, lam, li, total);
  }

  f2b_kernel<<<4096, 256, 0, stream>>>(w_out, wl, 4194304);
  final_norm<<<2048, 256, 0, stream>>>(total, x, alpha, flw, ybf);
  gemm_bt_f32<<<dim3(16, 16), 256, 0, stream>>>(ybf, wl, (float*)d_out);
}

// Round 5
// 636.703 us; speedup vs baseline: 1.8913x; 1.1329x over previous
//
#include <hip/hip_runtime.h>

typedef unsigned short ushort_t;
typedef __attribute__((ext_vector_type(8))) short bf16x8;
typedef __attribute__((ext_vector_type(4))) short bf16x4;
typedef __attribute__((ext_vector_type(4))) float f32x4;
typedef __attribute__((ext_vector_type(4))) unsigned short u16x4;
typedef __attribute__((ext_vector_type(4))) unsigned int u32x4;

#define DEV __device__ __forceinline__

// ---------- helpers ----------
DEV ushort_t f2bf(float f) {
  union { float f; unsigned int u; } a; a.f = f;
  unsigned int u = a.u;
  unsigned int r = (u + 0x7fffu + ((u >> 16) & 1u)) >> 16;  // RNE
  return (ushort_t)r;
}
DEV float bf2f(ushort_t b) {
  union { float f; unsigned int u; } a; a.u = ((unsigned int)b) << 16;
  return a.f;
}
DEV void gload_lds16(const void* g, void* l) {
  __builtin_amdgcn_global_load_lds((const __attribute__((address_space(1))) void*)g,
                                   (__attribute__((address_space(3))) void*)l, 16, 0, 0);
}
// hardware transpose read: lane l, elem j <- lds_elems[(l&15) + j*16 + (l>>4)*64]
DEV bf16x4 tr16(const ushort_t* l) {
  unsigned a = (unsigned)(unsigned long long)(const __attribute__((address_space(3))) ushort_t*)l;
  bf16x4 d;
  asm volatile("ds_read_b64_tr_b16 %0, %1" : "=v"(d) : "v"(a));
  return d;
}
DEV bf16x8 ldsb128(const ushort_t* l) {
  unsigned a = (unsigned)(unsigned long long)(const __attribute__((address_space(3))) ushort_t*)l;
  bf16x8 d;
  asm volatile("ds_read_b128 %0, %1" : "=v"(d) : "v"(a));
  return d;
}

// ---------- f32 -> bf16 convert ----------
__global__ __launch_bounds__(256) void f2b_kernel(const float* __restrict__ in,
                                                  ushort_t* __restrict__ out, int n) {
  int base = (blockIdx.x * 256 + threadIdx.x) * 4;
  if (base >= n) return;
  f32x4 v = *(const f32x4*)(in + base);
  u16x4 o;
  o.x = f2bf(v.x); o.y = f2bf(v.y); o.z = f2bf(v.z); o.w = f2bf(v.w);
  *(u16x4*)(out + base) = o;
}

// fused 3-tensor convert (per-layer wq/wk/wv), each 4194304 elements
__global__ __launch_bounds__(256) void f2b3_kernel(const float* __restrict__ a, const float* __restrict__ b,
                                                   const float* __restrict__ c, ushort_t* __restrict__ out) {
  int id = blockIdx.x * 256 + threadIdx.x;
  int sel = id >> 20, k = (id & 1048575) * 4;
  const float* src = sel == 0 ? a : sel == 1 ? b : c;
  f32x4 v = *(const f32x4*)(src + k);
  u16x4 o;
  o.x = f2bf(v.x); o.y = f2bf(v.y); o.z = f2bf(v.z); o.w = f2bf(v.w);
  *(u16x4*)(out + (size_t)sel * 4194304 + k) = o;
}

// ---------- lambda weights ----------
__global__ void lam_kernel(const float* __restrict__ lambdas, float* __restrict__ lam) {
  if (threadIdx.x == 0 && blockIdx.x == 0) {
    float l0 = 1.f / (1.f + __expf(-lambdas[0]));
    float l1 = 1.f / (1.f + __expf(-lambdas[1]));
    float l2 = 1.f / (1.f + __expf(-lambdas[2]));
    float mean = (l0 + l1 + l2) * (1.f / 3.f);
    float d0 = l0 - mean, d1 = l1 - mean, d2 = l2 - mean;
    float var = (d0 * d0 + d1 * d1 + d2 * d2) * (1.f / 3.f);
    float rs = rsqrtf(var + 1e-5f);
    lam[0] = d0 * rs; lam[1] = d1 * rs; lam[2] = d2 * rs;
  }
}

// ---------- GEMM core: C[128x128 tile] = A[M,K] * B[N,K]^T, bf16, MFMA ----------
DEV void gemm_core(const ushort_t* __restrict__ A, const ushort_t* __restrict__ Bm,
                   ushort_t* lsA, ushort_t* lsB, int bm, int bn, f32x4 (&acc)[4][4]) {
  const int K = 2048;
  int tid = threadIdx.x;
  int w = tid >> 6, lane = tid & 63;
  int g = lane >> 4, r = lane & 15;
  int wm = w >> 1, wn = w & 1;
#pragma unroll
  for (int i = 0; i < 4; ++i)
#pragma unroll
    for (int j = 0; j < 4; ++j) acc[i][j] = 0.f;

  for (int kk = 0; kk < K; kk += 32) {
    __syncthreads();  // prev compute done before LDS overwrite
#pragma unroll
    for (int j2 = 0; j2 < 2; ++j2) {
      int eb = w * 1024 + j2 * 512;          // wave-uniform element base
      int ebl = eb + lane * 8;               // this lane's element
      int rr = ebl >> 5, cc = ebl & 31;
      gload_lds16(A + (size_t)(bm * 128 + rr) * K + kk + cc, lsA + eb);
      gload_lds16(Bm + (size_t)(bn * 128 + rr) * K + kk + cc, lsB + eb);
    }
    __syncthreads();  // vmcnt(0) drain -> LDS tile ready
    bf16x8 af[4], bfr[4];
#pragma unroll
    for (int i = 0; i < 4; ++i)
      af[i] = *(const bf16x8*)(lsA + (wm * 64 + i * 16 + r) * 32 + g * 8);
#pragma unroll
    for (int j = 0; j < 4; ++j)
      bfr[j] = *(const bf16x8*)(lsB + (wn * 64 + j * 16 + r) * 32 + g * 8);
#pragma unroll
    for (int i = 0; i < 4; ++i)
#pragma unroll
      for (int j = 0; j < 4; ++j)
        acc[i][j] = __builtin_amdgcn_mfma_f32_16x16x32_bf16(af[i], bfr[j], acc[i][j], 0, 0, 0);
  }
}

// fused QKV GEMM: grid.x = 48 (16 col-tiles x 3 outputs), grid.y = 16 row-tiles.
__global__ __launch_bounds__(256) void gemm_qkv(
    const ushort_t* __restrict__ A,
    const ushort_t* __restrict__ Bq, const ushort_t* __restrict__ Bk, const ushort_t* __restrict__ Bv,
    ushort_t* __restrict__ Cq, ushort_t* __restrict__ Ck, ushort_t* __restrict__ Cv, int Lkv) {
  __shared__ __align__(16) ushort_t lsA[4096];
  __shared__ __align__(16) ushort_t lsB[4096];
  int sel = blockIdx.x >> 4, bn = blockIdx.x & 15, bm = blockIdx.y;
  const ushort_t* Bm = (sel == 0) ? Bq : (sel == 1) ? Bk : Bv;
  ushort_t* C = (sel == 0) ? Cq : (sel == 1) ? Ck : Cv;
  int Lsel = (sel == 0) ? 1024 : Lkv;
  f32x4 acc[4][4];
  gemm_core(A, Bm, lsA, lsB, bm, bn, acc);
  int lane = threadIdx.x & 63, w = threadIdx.x >> 6;
  int g = lane >> 4, r = lane & 15, wm = w >> 1, wn = w & 1;
#pragma unroll
  for (int i = 0; i < 4; ++i)
#pragma unroll
    for (int j = 0; j < 4; ++j) {
      int row0 = bm * 128 + wm * 64 + i * 16 + g * 4;
      int col = bn * 128 + wn * 64 + j * 16 + r;
#pragma unroll
      for (int t = 0; t < 4; ++t) {
        int row = row0 + t;
        int b2 = row >> 10, t2 = row & 1023;
        C[(size_t)(b2 * Lsel + t2) * 2048 + col] = f2bf(acc[i][j][t]);
      }
    }
}

// single GEMM with f32 output (final projection)
__global__ __launch_bounds__(256) void gemm_bt_f32(
    const ushort_t* __restrict__ A, const ushort_t* __restrict__ Bm, float* __restrict__ C) {
  __shared__ __align__(16) ushort_t lsA[4096];
  __shared__ __align__(16) ushort_t lsB[4096];
  int bn = blockIdx.x, bm = blockIdx.y;
  f32x4 acc[4][4];
  gemm_core(A, Bm, lsA, lsB, bm, bn, acc);
  int lane = threadIdx.x & 63, w = threadIdx.x >> 6;
  int g = lane >> 4, r = lane & 15, wm = w >> 1, wn = w & 1;
#pragma unroll
  for (int i = 0; i < 4; ++i)
#pragma unroll
    for (int j = 0; j < 4; ++j) {
      int row0 = bm * 128 + wm * 64 + i * 16 + g * 4;
      int col = bn * 128 + wn * 64 + j * 16 + r;
#pragma unroll
      for (int t = 0; t < 4; ++t)
        C[(size_t)(row0 + t) * 2048 + col] = acc[i][j][t];
    }
}

// ---------- rope segment ----------
__global__ __launch_bounds__(256) void rope_seg(const ushort_t* __restrict__ src, ushort_t* __restrict__ dst,
                                                const float* __restrict__ cosT, const float* __restrict__ sinT,
                                                int Ls, int s0, int Ld, int dpos0, int cnt) {
  int bp = blockIdx.x;
  int b = bp / cnt, pidx = bp % cnt;
  int pos = dpos0 + pidx;
  int pi = threadIdx.x * 4;         // pair index 0..1023
  int h = pi >> 6, d = pi & 63;
  const ushort_t* s_ = src + ((size_t)(b * Ls + s0 + pidx) * 16 + h) * 128 + d;
  ushort_t* d_ = dst + ((size_t)(b * Ld + pos) * 16 + h) * 128 + d;
  f32x4 c4 = *(const f32x4*)(cosT + (size_t)pos * 64 + d);
  f32x4 s4 = *(const f32x4*)(sinT + (size_t)pos * 64 + d);
  u16x4 x1 = *(const u16x4*)(s_);
  u16x4 x2 = *(const u16x4*)(s_ + 64);
  u16x4 o1, o2;
#pragma unroll
  for (int k = 0; k < 4; ++k) {
    float a = bf2f(x1[k]), bb = bf2f(x2[k]);
    o1[k] = f2bf(a * c4[k] - bb * s4[k]);
    o2[k] = f2bf(a * s4[k] + bb * c4[k]);
  }
  *(u16x4*)d_ = o1;
  *(u16x4*)(d_ + 64) = o2;
}

// ---------- row copy segment ----------
__global__ __launch_bounds__(256) void copy_seg(const ushort_t* __restrict__ src, ushort_t* __restrict__ dst,
                                                int Ls, int s0, int Ld, int dpos0, int cnt) {
  int bp = blockIdx.x;
  int b = bp / cnt, pidx = bp % cnt;
  const u32x4* s = (const u32x4*)(src + (size_t)(b * Ls + s0 + pidx) * 2048);
  u32x4* d = (u32x4*)(dst + (size_t)(b * Ld + dpos0 + pidx) * 2048);
  d[threadIdx.x] = s[threadIdx.x];
}

// ---------- flash attention v3: dbuf LDS staging, counted vmcnt, batched LDS reads ----------
// Block = 4 waves, one (b,h) + 4 consecutive 16-row q-tiles. KV tile = 32 keys.
// K in LDS row-major [32][128] with XOR-swizzled 16B chunks (chunk ^= row&7).
// V in LDS subtiled [d/16=8][k/4=8][4][16] -> ds_read_b64_tr_b16 gives V^T A-frags.
// PV computes O^T = V^T * P^T so P^T (swapped-QK^T output) is the B-frag in-register.
__global__ __launch_bounds__(256) void attn_kernel(
    const ushort_t* __restrict__ Q, const ushort_t* __restrict__ Kc, const ushort_t* __restrict__ Vc,
    float* __restrict__ Oout, int Lk) {
  __shared__ __align__(16) ushort_t lsK[8192];  // 2 x 8 KB
  __shared__ __align__(16) ushort_t lsV[8192];  // 2 x 8 KB
  const float sc = 0.08838834764831843f;  // 1/sqrt(128)

  // XCD-aware swizzle: 512 blocks, 8 XCDs -> 64 consecutive logical blocks per XCD
  int bid = (int)blockIdx.x;
  int swz = (bid & 7) * 64 + (bid >> 3);

  int w = threadIdx.x >> 6, lane = threadIdx.x & 63;
  int wid = swz * 4 + w;
  int qt = wid & 63, h = (wid >> 6) & 15, b = wid >> 10;
  int bq = swz & 15;
  int g = lane >> 4, r = lane & 15;
  int off = Lk - 1024;

  // Q fragments (B-operand of QK^T: B[k][n=r], q-row = qt*16+r)
  const ushort_t* qbase = Q + ((size_t)(b * 1024 + qt * 16 + r) * 16 + h) * 128;
  bf16x8 qf[4];
#pragma unroll
  for (int c = 0; c < 4; ++c) qf[c] = *(const bf16x8*)(qbase + c * 32 + g * 8);

  // staging source pointers (pre-swizzled per-lane global addresses)
  int t = threadIdx.x;
  int krow0 = t >> 4,        kc0 = (t & 15) ^ (krow0 & 7);
  int krow1 = (t + 256) >> 4, kc1 = (t & 15) ^ (krow1 & 7);
  const ushort_t* srcK0 = Kc + ((size_t)(b * Lk + krow0) * 16 + h) * 128 + kc0 * 8;
  const ushort_t* srcK1 = Kc + ((size_t)(b * Lk + krow1) * 16 + h) * 128 + kc1 * 8;
  int L0 = t, L1 = t + 256;
  int vrow0 = ((L0 >> 3) & 7) * 4 + ((L0 >> 1) & 3), vd0 = (L0 >> 6) * 16 + (L0 & 1) * 8;
  int vrow1 = ((L1 >> 3) & 7) * 4 + ((L1 >> 1) & 3), vd1 = (L1 >> 6) * 16 + (L1 & 1) * 8;
  const ushort_t* srcV0 = Vc + ((size_t)(b * Lk + vrow0) * 16 + h) * 128 + vd0;
  const ushort_t* srcV1 = Vc + ((size_t)(b * Lk + vrow1) * 16 + h) * 128 + vd1;
  const size_t adv = 32 * 2048;  // 32 kv rows per tile

  auto STAGE = [&](int buf) {
    ushort_t* k0 = lsK + buf * 4096 + w * 512;
    ushort_t* v0 = lsV + buf * 4096 + w * 512;
    gload_lds16(srcK0, k0);
    gload_lds16(srcK1, k0 + 2048);
    gload_lds16(srcV0, v0);
    gload_lds16(srcV1, v0 + 2048);
    srcK0 += adv; srcK1 += adv; srcV0 += adv; srcV1 += adv;
  };

  float m_run = -1e30f, l_run = 0.f;
  f32x4 o[8];
#pragma unroll
  for (int c = 0; c < 8; ++c) o[c] = 0.f;

  int qp = qt * 16 + r + off;                         // causal limit for q=r
  int nkt_w = ((qt * 16 + 15 + off) >> 5) + 1;        // this wave's tiles
  int nkt_blk = (((bq * 4 + 3) * 16 + 15 + off) >> 5) + 1;  // block max

  STAGE(0);  // prologue

  for (int kt = 0; kt < nkt_blk; ++kt) {
    int cur = kt & 1;
    if (kt + 1 < nkt_blk) {
      STAGE(cur ^ 1);
      asm volatile("s_waitcnt vmcnt(4)" ::: "memory");
    } else {
      asm volatile("s_waitcnt vmcnt(0)" ::: "memory");
    }
    __builtin_amdgcn_s_barrier();
    __builtin_amdgcn_sched_barrier(0);
    if (kt < nkt_w) {
      const ushort_t* Kb = lsK + cur * 4096;
      const ushort_t* Vb = lsV + cur * 4096;
      // batched LDS reads: 8 K b128 first, then 16 V transpose reads
      bf16x8 kf[8];
#pragma unroll
      for (int ks = 0; ks < 2; ++ks)
#pragma unroll
        for (int c = 0; c < 4; ++c)
          kf[ks * 4 + c] = ldsb128(Kb + (ks * 16 + r) * 128 + ((c * 32 + g * 8) ^ ((r & 7) * 8)));
      bf16x4 vf[16];
#pragma unroll
      for (int i = 0; i < 16; ++i) vf[i] = tr16(Vb + i * 256);
      asm volatile("s_waitcnt lgkmcnt(15)" ::: "memory");  // 9 oldest done = all 8 K reads
      __builtin_amdgcn_sched_barrier(0);
      __builtin_amdgcn_s_setprio(1);
      f32x4 st[2];
      st[0] = 0.f; st[1] = 0.f;
#pragma unroll
      for (int ks = 0; ks < 2; ++ks)
#pragma unroll
        for (int c = 0; c < 4; ++c)
          st[ks] = __builtin_amdgcn_mfma_f32_16x16x32_bf16(kf[ks * 4 + c], qf[c], st[ks], 0, 0, 0);
      __builtin_amdgcn_s_setprio(0);
      // softmax over the 8 scores this lane holds (keys kt*32 + ks*16 + g*4 + j, q = r)
      float pvv[2][4];
      float pmax = -1e30f;
      int kp0 = kt * 32;
#pragma unroll
      for (int ks = 0; ks < 2; ++ks)
#pragma unroll
        for (int j = 0; j < 4; ++j) {
          int key = kp0 + ks * 16 + g * 4 + j;
          float s = st[ks][j] * sc;
          if (key > qp) s = -1e30f;
          pvv[ks][j] = s;
          pmax = fmaxf(pmax, s);
        }
      pmax = fmaxf(pmax, __shfl_xor(pmax, 16, 64));
      pmax = fmaxf(pmax, __shfl_xor(pmax, 32, 64));
      if (!__all(pmax <= m_run + 8.f)) {   // defer-max: rescale only when needed
        float mnew = fmaxf(m_run, pmax);
        float corr = __expf(m_run - mnew);
        l_run *= corr;
#pragma unroll
        for (int c = 0; c < 8; ++c)
#pragma unroll
          for (int tt = 0; tt < 4; ++tt) o[c][tt] *= corr;
        m_run = mnew;
      }
      float psum = 0.f;
      bf16x4 pf[2];
#pragma unroll
      for (int ks = 0; ks < 2; ++ks)
#pragma unroll
        for (int j = 0; j < 4; ++j) {
          float pe = __expf(pvv[ks][j] - m_run);
          psum += pe;
          pf[ks][j] = (short)f2bf(pe);
        }
      psum += __shfl_xor(psum, 16, 64);
      psum += __shfl_xor(psum, 32, 64);
      l_run += psum;
      asm volatile("s_waitcnt lgkmcnt(0)" ::: "memory");  // V transpose reads done
      __builtin_amdgcn_sched_barrier(0);
      __builtin_amdgcn_s_setprio(1);
      // PV: O^T[d][q] += V^T[d][k] * P^T[k][q]
#pragma unroll
      for (int dblk = 0; dblk < 8; ++dblk) {
        o[dblk] = __builtin_amdgcn_mfma_f32_16x16x16bf16_1k(vf[dblk * 2], pf[0], o[dblk], 0, 0, 0);
        o[dblk] = __builtin_amdgcn_mfma_f32_16x16x16bf16_1k(vf[dblk * 2 + 1], pf[1], o[dblk], 0, 0, 0);
      }
      __builtin_amdgcn_s_setprio(0);
    }
    __builtin_amdgcn_sched_barrier(0);
    __builtin_amdgcn_s_barrier();
  }
  // epilogue: O^T frag -> O[q = qt*16+r][d = dblk*16 + g*4 + t]
  float linv = 1.f / l_run;
  float* ob = Oout + ((size_t)(b * 1024 + qt * 16 + r) * 16 + h) * 128;
#pragma unroll
  for (int dblk = 0; dblk < 8; ++dblk) {
    f32x4 res;
#pragma unroll
    for (int tt = 0; tt < 4; ++tt) res[tt] = o[dblk][tt] * linv;
    *(f32x4*)(ob + dblk * 16 + g * 4) = res;
  }
}

// ---------- RMS norm of attn row + weighted accumulate into total ----------
template <int FIRST>
__global__ __launch_bounds__(256) void rms_accum(const float* __restrict__ attn, const float* __restrict__ lnw,
                                                 const float* __restrict__ lam, int li,
                                                 float* __restrict__ total) {
  int row = blockIdx.x;
  const float* a = attn + (size_t)row * 2048;
  int t8 = threadIdx.x * 8;
  f32x4 v0 = *(const f32x4*)(a + t8);
  f32x4 v1 = *(const f32x4*)(a + t8 + 4);
  float ss = v0.x * v0.x + v0.y * v0.y + v0.z * v0.z + v0.w * v0.w +
             v1.x * v1.x + v1.y * v1.y + v1.z * v1.z + v1.w * v1.w;
#pragma unroll
  for (int m = 1; m < 64; m <<= 1) ss += __shfl_xor(ss, m, 64);
  __shared__ float red[4];
  int w = threadIdx.x >> 6, lane = threadIdx.x & 63;
  if (lane == 0) red[w] = ss;
  __syncthreads();
  ss = red[0] + red[1] + red[2] + red[3];
  float s = rsqrtf(ss * (1.f / 2048.f) + 1e-5f) * lam[li];
  f32x4 w0 = *(const f32x4*)(lnw + t8);
  f32x4 w1 = *(const f32x4*)(lnw + t8 + 4);
  float* o = total + (size_t)row * 2048 + t8;
  f32x4 r0, r1;
#pragma unroll
  for (int k = 0; k < 4; ++k) { r0[k] = v0[k] * s * w0[k]; r1[k] = v1[k] * s * w1[k]; }
  if (!FIRST) {
    f32x4 p0 = *(const f32x4*)(o);
    f32x4 p1 = *(const f32x4*)(o + 4);
#pragma unroll
    for (int k = 0; k < 4; ++k) { r0[k] += p0[k]; r1[k] += p1[k]; }
  }
  *(f32x4*)(o) = r0;
  *(f32x4*)(o + 4) = r1;
}

// ---------- final: y = rms(total + alpha*x)*flw -> bf16 ----------
__global__ __launch_bounds__(256) void final_norm(const float* __restrict__ total, const float* __restrict__ x,
                                                  const float* __restrict__ alphap, const float* __restrict__ flw,
                                                  ushort_t* __restrict__ ybf) {
  int row = blockIdx.x;
  float al = alphap[0];
  int t8 = threadIdx.x * 8;
  const float* tp = total + (size_t)row * 2048 + t8;
  const float* xp = x + (size_t)row * 2048 + t8;
  f32x4 t0 = *(const f32x4*)(tp);
  f32x4 t1 = *(const f32x4*)(tp + 4);
  f32x4 x0 = *(const f32x4*)(xp);
  f32x4 x1 = *(const f32x4*)(xp + 4);
  float y[8];
#pragma unroll
  for (int k = 0; k < 4; ++k) { y[k] = t0[k] + al * x0[k]; y[4 + k] = t1[k] + al * x1[k]; }
  float ss = 0.f;
#pragma unroll
  for (int k = 0; k < 8; ++k) ss += y[k] * y[k];
#pragma unroll
  for (int m = 1; m < 64; m <<= 1) ss += __shfl_xor(ss, m, 64);
  __shared__ float red[4];
  int w = threadIdx.x >> 6, lane = threadIdx.x & 63;
  if (lane == 0) red[w] = ss;
  __syncthreads();
  ss = red[0] + red[1] + red[2] + red[3];
  float s = rsqrtf(ss * (1.f / 2048.f) + 1e-5f);
  f32x4 w0 = *(const f32x4*)(flw + t8);
  f32x4 w1 = *(const f32x4*)(flw + t8 + 4);
  u16x4 o0, o1;
#pragma unroll
  for (int k = 0; k < 4; ++k) {
    o0[k] = f2bf(y[k] * s * w0[k]);
    o1[k] = f2bf(y[4 + k] * s * w1[k]);
  }
  *(u16x4*)(ybf + (size_t)row * 2048 + t8) = o0;
  *(u16x4*)(ybf + (size_t)row * 2048 + t8 + 4) = o1;
}

// ---------- host ----------
extern "C" void kernel_launch(void* const* d_in, const int* in_sizes, int n_in,
                              void* d_out, int out_size, void* d_ws, size_t ws_size,
                              hipStream_t stream) {
  const float* x = (const float*)d_in[0];
  const float* cosT = (const float*)d_in[1];
  const float* sinT = (const float*)d_in[2];
  const float* wq = (const float*)d_in[3];
  const float* wk = (const float*)d_in[4];
  const float* wv = (const float*)d_in[5];
  const float* lnw = (const float*)d_in[6];
  const float* lambdas = (const float*)d_in[7];
  const float* w_out = (const float*)d_in[8];
  const float* flw = (const float*)d_in[9];
  const float* alpha = (const float*)d_in[10];

  const size_t ME = 4194304ull;  // 2048*2048 elements
  char* p = (char*)d_ws;
  size_t off = 0;
  auto alc = [&](size_t bytes) -> void* {
    void* r = p + off;
    off += (bytes + 255) & ~(size_t)255;
    return r;
  };
  ushort_t* xb = (ushort_t*)alc(ME * 2);        // 8 MB
  ushort_t* wl = (ushort_t*)alc(3 * ME * 2);    // 24 MB (per-layer wq,wk,wv; later w_out)
  ushort_t* q = (ushort_t*)alc(ME * 2);         // 8 MB (roped in place; later ybf)
  ushort_t* K0 = (ushort_t*)alc(ME * 2);        // 8 MB
  ushort_t* K1 = (ushort_t*)alc(2 * ME * 2);    // 16 MB
  ushort_t* K2 = (ushort_t*)alc(4 * ME * 2);    // 32 MB
  ushort_t* V0 = (ushort_t*)alc(ME * 2);        // 8 MB
  ushort_t* V1 = (ushort_t*)alc(2 * ME * 2);    // 16 MB
  ushort_t* V2 = (ushort_t*)alc(4 * ME * 2);    // 32 MB
  float* attn = (float*)alc(ME * 4);            // 16 MB
  float* total = (float*)alc(ME * 4);           // 16 MB
  float* lam = (float*)alc(256);
  ushort_t* ybf = q;                             // alias: q dead before final_norm

  f2b_kernel<<<4096, 256, 0, stream>>>(x, xb, 4194304);
  lam_kernel<<<1, 64, 0, stream>>>(lambdas, lam);

  ushort_t* Kc[3] = {K0, K1, K2};
  ushort_t* Vc[3] = {V0, V1, V2};

  for (int li = 0; li < 3; ++li) {
    int L = 1024 << li;
    size_t woff = (size_t)li * ME;
    f2b3_kernel<<<12288, 256, 0, stream>>>(wq + woff, wk + woff, wv + woff, wl);
    gemm_qkv<<<dim3(48, 16), 256, 0, stream>>>(xb, wl, wl + ME, wl + 2 * ME,
                                               q, Kc[li], Vc[li], L);
    rope_seg<<<2048, 256, 0, stream>>>(q, q, cosT, sinT, 1024, 0, 1024, 0, 1024);
    rope_seg<<<2048, 256, 0, stream>>>(Kc[li], Kc[li], cosT, sinT, L, 0, L, 0, 1024);
    if (li == 1) {
      rope_seg<<<2048, 256, 0, stream>>>(K0, K1, cosT, sinT, 1024, 0, 2048, 1024, 1024);
      copy_seg<<<2048, 256, 0, stream>>>(V0, V1, 1024, 0, 2048, 1024, 1024);
    } else if (li == 2) {
      copy_seg<<<2048, 256, 0, stream>>>(K1, K2, 2048, 1024, 4096, 1024, 1024);
      rope_seg<<<4096, 256, 0, stream>>>(K1, K2, cosT, sinT, 2048, 0, 4096, 2048, 2048);
      copy_seg<<<2048, 256, 0, stream>>>(V1, V2, 2048, 1024, 4096, 1024, 1024);
      copy_seg<<<4096, 256, 0, stream>>>(V1, V2, 2048, 0, 4096, 2048, 2048);
    }
    attn_kernel<<<512, 256, 0, stream>>>(q, Kc[li], Vc[li], attn, L);
    if (li == 0)
      rms_accum<1><<<2048, 256, 0, stream>>>(attn, lnw, lam, 0, total);
    else
      rms_accum<0><<<2048, 256, 0, stream>>>(attn, lnw + (size_t)li * 2048, lam, li, total);
  }

  f2b_kernel<<<4096, 256, 0, stream>>>(w_out, wl, 4194304);
  final_norm<<<2048, 256, 0, stream>>>(total, x, alpha, flw, ybf);
  gemm_bt_f32<<<dim3(16, 16), 256, 0, stream>>>(ybf, wl, (float*)d_out);
}